// Round 7
// baseline (3871.028 us; speedup 1.0000x reference)
//
#include <hip/hip_runtime.h>
#include <hip/hip_bf16.h>
#include <math.h>

#define HIDDEN 256
#define SEQ 2048
#define BATCH 64
#define INSZ 128
#define OUTSZ 64
#define DTC 0.05f

typedef _Float16 h2 __attribute__((ext_vector_type(2)));

// ---------------- K0: complexity net + alphas ----------------
__global__ __launch_bounds__(1024) void prep_kernel(
    const float* __restrict__ x, const float* __restrict__ cw1, const float* __restrict__ cb1,
    const float* __restrict__ cw2, const float* __restrict__ cb2,
    const float* __restrict__ tau_b, const float* __restrict__ tmw, const float* __restrict__ tmb,
    float* __restrict__ alphas)   // [3][64]
{
    __shared__ float p_lds[8][128];
    __shared__ float xm[128];
    __shared__ float t1[64];
    int b = blockIdx.x;
    int tid = threadIdx.x;
    int c = tid & 127, sh = tid >> 7;
    const float* xb = x + (size_t)b * SEQ * INSZ;
    float s = 0.f;
    for (int t = sh * 256; t < (sh + 1) * 256; ++t) s += xb[(size_t)t * INSZ + c];
    p_lds[sh][c] = s;
    __syncthreads();
    if (tid < 128) {
        float m = 0.f;
        #pragma unroll
        for (int i = 0; i < 8; ++i) m += p_lds[i][tid];
        xm[tid] = m / (float)SEQ;
    }
    __syncthreads();
    if (tid < 64) {
        float acc = cb1[tid];
        for (int k = 0; k < 128; ++k) acc += xm[k] * cw1[tid * 128 + k];
        t1[tid] = fmaxf(acc, 0.f);
    }
    __syncthreads();
    if (tid == 0) {
        float acc = cb2[0];
        for (int k = 0; k < 64; ++k) acc += t1[k] * cw2[k];
        float comp = 1.f / (1.f + expf(-acc));
        for (int i = 0; i < 3; ++i) {
            float lg[4], mx = -1e30f;
            for (int j = 0; j < 4; ++j) { lg[j] = comp * tmw[i * 4 + j] + tmb[i * 4 + j]; mx = fmaxf(mx, lg[j]); }
            float den = 0.f;
            for (int j = 0; j < 4; ++j) { lg[j] = expf(lg[j] - mx); den += lg[j]; }
            float mt = 0.f;
            for (int j = 0; j < 4; ++j) mt += tau_b[i * 4 + j] * (lg[j] / den);
            alphas[i * 64 + b] = expf(-DTC / mt);
        }
    }
}

// ---------------- Wf = W_in0 @ pw  (256x128), bf = W_in0 @ pb + bias0 ----------------
__global__ __launch_bounds__(128) void wf_kernel(
    const float* __restrict__ W_in0, const float* __restrict__ pw,
    const float* __restrict__ pb, const float* __restrict__ bias0,
    float* __restrict__ Wf, float* __restrict__ bf)
{
    __shared__ float wrow[256];
    int j = blockIdx.x, k = threadIdx.x;
    for (int m = k; m < 256; m += 128) wrow[m] = W_in0[j * 256 + m];
    __syncthreads();
    float s = 0.f;
    for (int m = 0; m < 256; ++m) s = fmaf(wrow[m], pw[m * 128 + k], s);
    Wf[j * 128 + k] = s;
    if (k == 0) {
        float sb = bias0[j];
        for (int m = 0; m < 256; ++m) sb = fmaf(wrow[m], pb[m], sb);
        bf[j] = sb;
    }
}

// ---------------- streaming register-weight GEMM (unchanged, fp32) ----------------
template<int KQ, int NR>
__global__ __launch_bounds__(512) void gemm_stream(
    const float* A, const float* __restrict__ W, const float* __restrict__ bias,
    float* C, int rows_per_wg)
{
    constexpr int K = KQ * 64;
    constexpr int JB = 8 / KQ;
    __shared__ float a_lds[4 * K];
    __shared__ float p_lds[KQ][4][256];
    __shared__ float bias_l[256];
    int tid = threadIdx.x;
    int w = tid >> 6, l = tid & 63;
    int q = w % KQ, jb = w / KQ;

    float4 wr[NR][16];
    #pragma unroll
    for (int r = 0; r < NR; ++r) {
        int j = jb * 64 + l + r * (JB * 64);
        const float4* wp = (const float4*)(W + (size_t)j * K + q * 64);
        #pragma unroll
        for (int m = 0; m < 16; ++m) wr[r][m] = wp[m];
    }
    if (tid < 256) bias_l[tid] = bias[tid];

    size_t row0 = (size_t)blockIdx.x * rows_per_wg;
    for (int it = 0; it < rows_per_wg; it += 4) {
        size_t m0 = row0 + it;
        __syncthreads();
        #pragma unroll
        for (int e = 0; e < K / 128; ++e)
            a_lds[tid + e * 512] = A[m0 * K + tid + e * 512];
        __syncthreads();

        float acc[4][NR];
        #pragma unroll
        for (int r4 = 0; r4 < 4; ++r4)
            #pragma unroll
            for (int r = 0; r < NR; ++r) acc[r4][r] = 0.f;

        #pragma unroll
        for (int r4 = 0; r4 < 4; ++r4) {
            const float4* hp = (const float4*)(a_lds + r4 * K + q * 64);
            #pragma unroll
            for (int m = 0; m < 16; ++m) {
                float4 hv = hp[m];
                #pragma unroll
                for (int r = 0; r < NR; ++r) {
                    acc[r4][r] = fmaf(wr[r][m].x, hv.x, acc[r4][r]);
                    acc[r4][r] = fmaf(wr[r][m].y, hv.y, acc[r4][r]);
                    acc[r4][r] = fmaf(wr[r][m].z, hv.z, acc[r4][r]);
                    acc[r4][r] = fmaf(wr[r][m].w, hv.w, acc[r4][r]);
                }
            }
        }
        #pragma unroll
        for (int r4 = 0; r4 < 4; ++r4)
            #pragma unroll
            for (int r = 0; r < NR; ++r)
                p_lds[q][r4][jb * 64 + l + r * (JB * 64)] = acc[r4][r];
        __syncthreads();
        if (tid < 256) {
            #pragma unroll
            for (int r4 = 0; r4 < 4; ++r4) {
                float s2 = bias_l[tid];
                #pragma unroll
                for (int qq = 0; qq < KQ; ++qq) s2 += p_lds[qq][r4][tid];
                C[(m0 + r4) * 256 + tid] = s2;
            }
        }
    }
}

__device__ __forceinline__ float fast_tanh(float x) {
    float ex = __expf(2.f * x);                 // v_exp based
    float r = __builtin_amdgcn_rcpf(ex + 1.f);  // v_rcp_f32
    return 1.f - 2.f * r;                       // ex=inf -> 1, ex=0 -> -1
}

// cross-lane add helpers: xor1/xor2 on VALU (DPP quad_perm) — no LDS pipe
__device__ __forceinline__ float dpp_add_xor1(float v) {
    int x = __builtin_amdgcn_update_dpp(0, __builtin_bit_cast(int, v), 0xB1, 0xF, 0xF, false); // quad_perm [1,0,3,2]
    return v + __builtin_bit_cast(float, x);
}
__device__ __forceinline__ float dpp_add_xor2(float v) {
    int x = __builtin_amdgcn_update_dpp(0, __builtin_bit_cast(int, v), 0x4E, 0xF, 0xF, false); // quad_perm [2,3,0,1]
    return v + __builtin_bit_cast(float, x);
}

// LDS-only barrier: waits ds ops (lgkmcnt) but leaves global loads/stores
// in flight across the barrier (vmcnt NOT drained — the T4 counted-vmcnt idiom).
// __syncthreads would emit s_waitcnt vmcnt(0) and expose prefetch latency every step.
__device__ __forceinline__ void barrier_lds_only() {
    asm volatile("s_waitcnt lgkmcnt(0)\n\ts_barrier" ::: "memory");
}

#if __has_builtin(__builtin_amdgcn_fdot2)
#define FDOT2(a, b, c) __builtin_amdgcn_fdot2((a), (b), (c), false)
#else
#define FDOT2(a, b, c) fmaf((float)(a).x, (float)(b).x, fmaf((float)(a).y, (float)(b).y, (c)))
#endif

// ---------------- scan: 256 threads, thread tid owns output o=tid ----------------
// group g = tid>>2 (outputs 4g..4g+3), k-seg kq = tid&3 (k in [64kq, 64kq+64))
// 4-lane DPP-only reduce (xor1+xor2), ONE 4-wave LDS-only barrier per step.
__global__ __launch_bounds__(256, 1) void scan_kernel(
    float* buf,                       // [B][S][256]: in = ext, out = h_seq (in place)
    const float* __restrict__ W_rec,  // [256][256]
    const float* __restrict__ alphas, // [64]
    float* __restrict__ h_carry,      // [64][256]
    int layer, int write_all)
{
    __shared__ alignas(16) unsigned short h16[2][4 * 72];  // 2 x 576B
    int b = blockIdx.x;
    int tid = threadIdx.x;
    int g = tid >> 2;       // 0..63
    int kq = tid & 3;       // 0..3
    int j = kq;             // output within group this lane finalizes
    int o = tid;            // == g*4 + j

    // weights rows 4g..4g+3, cols [64kq, 64kq+64), as 32 half2 per row = 128 VGPR
    h2 wh[4][32];
    #pragma unroll
    for (int jj = 0; jj < 4; ++jj) {
        const float4* wp = (const float4*)(W_rec + (size_t)(g * 4 + jj) * 256 + kq * 64);
        #pragma unroll
        for (int m = 0; m < 16; ++m) {
            float4 wv = wp[m];
            wh[jj][2 * m]     = __builtin_bit_cast(h2, __builtin_amdgcn_cvt_pkrtz(wv.x, wv.y));
            wh[jj][2 * m + 1] = __builtin_bit_cast(h2, __builtin_amdgcn_cvt_pkrtz(wv.z, wv.w));
        }
    }

    float alpha = alphas[b];
    float onema = 1.f - alpha;
    float* bb = buf + (size_t)b * SEQ * HIDDEN;

    float h_reg = (layer == 0) ? 0.f : h_carry[b * 256 + o];
    char* hbase = (char*)&h16[0][0];
    // initial h into buffer 0: seg o>>6, slot o&63
    *(_Float16*)(hbase + (o >> 6) * 144 + (o & 63) * 2) = (_Float16)h_reg;
    float e_cur = bb[o];                       // ext[0]
    float e_n1  = bb[(size_t)1 * HIDDEN + o];  // ext[1]
    __syncthreads();

    int cur = 0;
    for (int t = 0; t < SEQ; ++t) {
        float e_n2 = 0.f;
        if (t + 2 < SEQ) e_n2 = bb[(size_t)(t + 2) * HIDDEN + o];  // 2-ahead prefetch

        // read 64 f16 of h (this thread's k-segment): 8 x ds_read_b128, broadcast x16
        const uint4* hp = (const uint4*)(hbase + cur * 576 + kq * 144);
        float a0 = 0.f, a1 = 0.f, a2 = 0.f, a3 = 0.f;
        #pragma unroll
        for (int m = 0; m < 8; ++m) {
            uint4 q = hp[m];
            h2 hv0 = __builtin_bit_cast(h2, q.x);
            h2 hv1 = __builtin_bit_cast(h2, q.y);
            h2 hv2 = __builtin_bit_cast(h2, q.z);
            h2 hv3 = __builtin_bit_cast(h2, q.w);
            a0 = FDOT2(wh[0][4 * m], hv0, a0); a0 = FDOT2(wh[0][4 * m + 1], hv1, a0);
            a0 = FDOT2(wh[0][4 * m + 2], hv2, a0); a0 = FDOT2(wh[0][4 * m + 3], hv3, a0);
            a1 = FDOT2(wh[1][4 * m], hv0, a1); a1 = FDOT2(wh[1][4 * m + 1], hv1, a1);
            a1 = FDOT2(wh[1][4 * m + 2], hv2, a1); a1 = FDOT2(wh[1][4 * m + 3], hv3, a1);
            a2 = FDOT2(wh[2][4 * m], hv0, a2); a2 = FDOT2(wh[2][4 * m + 1], hv1, a2);
            a2 = FDOT2(wh[2][4 * m + 2], hv2, a2); a2 = FDOT2(wh[2][4 * m + 3], hv3, a2);
            a3 = FDOT2(wh[3][4 * m], hv0, a3); a3 = FDOT2(wh[3][4 * m + 1], hv1, a3);
            a3 = FDOT2(wh[3][4 * m + 2], hv2, a3); a3 = FDOT2(wh[3][4 * m + 3], hv3, a3);
        }
        // reduce over the 4 k-segments: 2 DPP levels, no LDS
        a0 = dpp_add_xor1(a0); a1 = dpp_add_xor1(a1); a2 = dpp_add_xor1(a2); a3 = dpp_add_xor1(a3);
        a0 = dpp_add_xor2(a0); a1 = dpp_add_xor2(a1); a2 = dpp_add_xor2(a2); a3 = dpp_add_xor2(a3);
        float acc = (j == 0) ? a0 : (j == 1) ? a1 : (j == 2) ? a2 : a3;

        float act = fast_tanh(acc + e_cur);
        h_reg = alpha * h_reg + onema * act;
        *(_Float16*)(hbase + (cur ^ 1) * 576 + (o >> 6) * 144 + (o & 63) * 2) = (_Float16)h_reg;
        if (write_all) bb[(size_t)t * HIDDEN + o] = h_reg;   // in-place h over consumed ext
        barrier_lds_only();   // lgkmcnt(0)+s_barrier; global ops stay in flight
        cur ^= 1;
        e_cur = e_n1;
        e_n1 = e_n2;
    }
    h_carry[b * 256 + o] = h_reg;
}

// ---------------- final projection from h_carry ----------------
__global__ __launch_bounds__(256) void outproj_kernel(
    const float* __restrict__ h_carry, const float* __restrict__ ow, const float* __restrict__ ob,
    float* __restrict__ out)
{
    __shared__ float h_l[256];
    __shared__ float p_lds[4][64];
    int b = blockIdx.x;
    int tid = threadIdx.x;
    h_l[tid] = h_carry[b * 256 + tid];
    __syncthreads();
    int o = tid & 63, qq = tid >> 6;
    float s = 0.f;
    const float4* wp = (const float4*)(ow + o * 256 + qq * 64);
    const float4* hp = (const float4*)(h_l + qq * 64);
    #pragma unroll
    for (int m = 0; m < 16; ++m) {
        float4 wv = wp[m]; float4 hv = hp[m];
        s = fmaf(wv.x, hv.x, s); s = fmaf(wv.y, hv.y, s);
        s = fmaf(wv.z, hv.z, s); s = fmaf(wv.w, hv.w, s);
    }
    p_lds[qq][o] = s;
    __syncthreads();
    if (tid < 64)
        out[b * 64 + tid] = p_lds[0][tid] + p_lds[1][tid] + p_lds[2][tid] + p_lds[3][tid] + ob[tid];
}

extern "C" void kernel_launch(void* const* d_in, const int* in_sizes, int n_in,
                              void* d_out, int out_size, void* d_ws, size_t ws_size,
                              hipStream_t stream)
{
    const float* x     = (const float*)d_in[0];
    const float* cw1   = (const float*)d_in[1];
    const float* cb1   = (const float*)d_in[2];
    const float* cw2   = (const float*)d_in[3];
    const float* cb2   = (const float*)d_in[4];
    const float* pw    = (const float*)d_in[5];
    const float* pb    = (const float*)d_in[6];
    const float* W_rec = (const float*)d_in[7];
    const float* W_in  = (const float*)d_in[8];
    const float* bias  = (const float*)d_in[9];
    const float* tau_b = (const float*)d_in[10];
    const float* tmw   = (const float*)d_in[11];
    const float* tmb   = (const float*)d_in[12];
    const float* ow    = (const float*)d_in[13];
    const float* ob    = (const float*)d_in[14];
    float* out = (float*)d_out;

    char* ws = (char*)d_ws;
    float* alphas  = (float*)ws;                       // 192 f
    float* h_carry = (float*)(ws + 4096);              // 64*256 f
    float* bf      = (float*)(ws + 69632);             // 256 f
    float* Wf      = (float*)(ws + 70656);             // 256*128 f
    float* buf     = (float*)(ws + 1048576);           // [64][2048][256] f32 = 134.2MB

    const int M = BATCH * SEQ;          // 131072 rows
    const int ROWS_PER_WG = M / 256;    // 512

    prep_kernel<<<64, 1024, 0, stream>>>(x, cw1, cb1, cw2, cb2, tau_b, tmw, tmb, alphas);
    wf_kernel<<<256, 128, 0, stream>>>(W_in, pw, pb, bias, Wf, bf);

    // layer 0 ext = x @ Wf.T + bf  (input projection fused away)
    gemm_stream<2, 1><<<256, 512, 0, stream>>>(x, Wf, bf, buf, ROWS_PER_WG);
    scan_kernel<<<64, 256, 0, stream>>>(buf, W_rec, alphas, h_carry, 0, 1);

    gemm_stream<4, 2><<<256, 512, 0, stream>>>(buf, W_in + (size_t)1 * HIDDEN * HIDDEN,
                                               bias + 1 * HIDDEN, buf, ROWS_PER_WG);
    scan_kernel<<<64, 256, 0, stream>>>(buf, W_rec + (size_t)1 * HIDDEN * HIDDEN,
                                        alphas + 64, h_carry, 1, 1);

    gemm_stream<4, 2><<<256, 512, 0, stream>>>(buf, W_in + (size_t)2 * HIDDEN * HIDDEN,
                                               bias + 2 * HIDDEN, buf, ROWS_PER_WG);
    scan_kernel<<<64, 256, 0, stream>>>(buf, W_rec + (size_t)2 * HIDDEN * HIDDEN,
                                        alphas + 128, h_carry, 2, 0);

    outproj_kernel<<<64, 256, 0, stream>>>(h_carry, ow, ob, out);
}

// Round 8
// 3605.217 us; speedup vs baseline: 1.0737x; 1.0737x over previous
//
#include <hip/hip_runtime.h>
#include <hip/hip_bf16.h>
#include <math.h>
#include <type_traits>

#define HIDDEN 256
#define SEQ 2048
#define BATCH 64
#define INSZ 128
#define OUTSZ 64
#define DTC 0.05f

typedef _Float16 h2 __attribute__((ext_vector_type(2)));

// ---------------- K0: complexity net + alphas ----------------
__global__ __launch_bounds__(1024) void prep_kernel(
    const float* __restrict__ x, const float* __restrict__ cw1, const float* __restrict__ cb1,
    const float* __restrict__ cw2, const float* __restrict__ cb2,
    const float* __restrict__ tau_b, const float* __restrict__ tmw, const float* __restrict__ tmb,
    float* __restrict__ alphas)   // [3][64]
{
    __shared__ float p_lds[8][128];
    __shared__ float xm[128];
    __shared__ float t1[64];
    int b = blockIdx.x;
    int tid = threadIdx.x;
    int c = tid & 127, sh = tid >> 7;
    const float* xb = x + (size_t)b * SEQ * INSZ;
    float s = 0.f;
    for (int t = sh * 256; t < (sh + 1) * 256; ++t) s += xb[(size_t)t * INSZ + c];
    p_lds[sh][c] = s;
    __syncthreads();
    if (tid < 128) {
        float m = 0.f;
        #pragma unroll
        for (int i = 0; i < 8; ++i) m += p_lds[i][tid];
        xm[tid] = m / (float)SEQ;
    }
    __syncthreads();
    if (tid < 64) {
        float acc = cb1[tid];
        for (int k = 0; k < 128; ++k) acc += xm[k] * cw1[tid * 128 + k];
        t1[tid] = fmaxf(acc, 0.f);
    }
    __syncthreads();
    if (tid == 0) {
        float acc = cb2[0];
        for (int k = 0; k < 64; ++k) acc += t1[k] * cw2[k];
        float comp = 1.f / (1.f + expf(-acc));
        for (int i = 0; i < 3; ++i) {
            float lg[4], mx = -1e30f;
            for (int j = 0; j < 4; ++j) { lg[j] = comp * tmw[i * 4 + j] + tmb[i * 4 + j]; mx = fmaxf(mx, lg[j]); }
            float den = 0.f;
            for (int j = 0; j < 4; ++j) { lg[j] = expf(lg[j] - mx); den += lg[j]; }
            float mt = 0.f;
            for (int j = 0; j < 4; ++j) mt += tau_b[i * 4 + j] * (lg[j] / den);
            alphas[i * 64 + b] = expf(-DTC / mt);
        }
    }
}

// ---------------- Wf = W_in0 @ pw  (256x128), bf = W_in0 @ pb + bias0 ----------------
__global__ __launch_bounds__(128) void wf_kernel(
    const float* __restrict__ W_in0, const float* __restrict__ pw,
    const float* __restrict__ pb, const float* __restrict__ bias0,
    float* __restrict__ Wf, float* __restrict__ bf)
{
    __shared__ float wrow[256];
    int j = blockIdx.x, k = threadIdx.x;
    for (int m = k; m < 256; m += 128) wrow[m] = W_in0[j * 256 + m];
    __syncthreads();
    float s = 0.f;
    for (int m = 0; m < 256; ++m) s = fmaf(wrow[m], pw[m * 128 + k], s);
    Wf[j * 128 + k] = s;
    if (k == 0) {
        float sb = bias0[j];
        for (int m = 0; m < 256; ++m) sb = fmaf(wrow[m], pb[m], sb);
        bf[j] = sb;
    }
}

// ---------------- streaming register-weight GEMM (unchanged, fp32) ----------------
template<int KQ, int NR>
__global__ __launch_bounds__(512) void gemm_stream(
    const float* A, const float* __restrict__ W, const float* __restrict__ bias,
    float* C, int rows_per_wg)
{
    constexpr int K = KQ * 64;
    constexpr int JB = 8 / KQ;
    __shared__ float a_lds[4 * K];
    __shared__ float p_lds[KQ][4][256];
    __shared__ float bias_l[256];
    int tid = threadIdx.x;
    int w = tid >> 6, l = tid & 63;
    int q = w % KQ, jb = w / KQ;

    float4 wr[NR][16];
    #pragma unroll
    for (int r = 0; r < NR; ++r) {
        int j = jb * 64 + l + r * (JB * 64);
        const float4* wp = (const float4*)(W + (size_t)j * K + q * 64);
        #pragma unroll
        for (int m = 0; m < 16; ++m) wr[r][m] = wp[m];
    }
    if (tid < 256) bias_l[tid] = bias[tid];

    size_t row0 = (size_t)blockIdx.x * rows_per_wg;
    for (int it = 0; it < rows_per_wg; it += 4) {
        size_t m0 = row0 + it;
        __syncthreads();
        #pragma unroll
        for (int e = 0; e < K / 128; ++e)
            a_lds[tid + e * 512] = A[m0 * K + tid + e * 512];
        __syncthreads();

        float acc[4][NR];
        #pragma unroll
        for (int r4 = 0; r4 < 4; ++r4)
            #pragma unroll
            for (int r = 0; r < NR; ++r) acc[r4][r] = 0.f;

        #pragma unroll
        for (int r4 = 0; r4 < 4; ++r4) {
            const float4* hp = (const float4*)(a_lds + r4 * K + q * 64);
            #pragma unroll
            for (int m = 0; m < 16; ++m) {
                float4 hv = hp[m];
                #pragma unroll
                for (int r = 0; r < NR; ++r) {
                    acc[r4][r] = fmaf(wr[r][m].x, hv.x, acc[r4][r]);
                    acc[r4][r] = fmaf(wr[r][m].y, hv.y, acc[r4][r]);
                    acc[r4][r] = fmaf(wr[r][m].z, hv.z, acc[r4][r]);
                    acc[r4][r] = fmaf(wr[r][m].w, hv.w, acc[r4][r]);
                }
            }
        }
        #pragma unroll
        for (int r4 = 0; r4 < 4; ++r4)
            #pragma unroll
            for (int r = 0; r < NR; ++r)
                p_lds[q][r4][jb * 64 + l + r * (JB * 64)] = acc[r4][r];
        __syncthreads();
        if (tid < 256) {
            #pragma unroll
            for (int r4 = 0; r4 < 4; ++r4) {
                float s2 = bias_l[tid];
                #pragma unroll
                for (int qq = 0; qq < KQ; ++qq) s2 += p_lds[qq][r4][tid];
                C[(m0 + r4) * 256 + tid] = s2;
            }
        }
    }
}

__device__ __forceinline__ float fast_tanh(float x) {
    float ex = __expf(2.f * x);                 // v_exp based
    float r = __builtin_amdgcn_rcpf(ex + 1.f);  // v_rcp_f32
    return 1.f - 2.f * r;                       // ex=inf -> 1, ex=0 -> -1
}

// cross-lane add helpers: xor1/xor2 on VALU (DPP quad_perm) — no LDS pipe
__device__ __forceinline__ float dpp_add_xor1(float v) {
    int x = __builtin_amdgcn_update_dpp(0, __builtin_bit_cast(int, v), 0xB1, 0xF, 0xF, false); // quad_perm [1,0,3,2]
    return v + __builtin_bit_cast(float, x);
}
__device__ __forceinline__ float dpp_add_xor2(float v) {
    int x = __builtin_amdgcn_update_dpp(0, __builtin_bit_cast(int, v), 0x4E, 0xF, 0xF, false); // quad_perm [2,3,0,1]
    return v + __builtin_bit_cast(float, x);
}

// LDS-only barrier: waits ds ops (lgkmcnt) but leaves global loads/stores in flight.
__device__ __forceinline__ void barrier_lds_only() {
    asm volatile("s_waitcnt lgkmcnt(0)\n\ts_barrier" ::: "memory");
}

#if __has_builtin(__builtin_amdgcn_fdot2)
#define FDOT2(a, b, c) __builtin_amdgcn_fdot2((a), (b), (c), false)
#else
#define FDOT2(a, b, c) fmaf((float)(a).x, (float)(b).x, fmaf((float)(a).y, (float)(b).y, (c)))
#endif

// ---------------- scan: 256 threads, thread tid owns output o=tid ----------------
// group g = tid>>2 (outputs 4g..4g+3), k-seg kq = tid&3 (k in [64kq, 64kq+64))
// All 8 ds_read_b128 hoisted into named regs (in flight together); time loop
// unrolled x2 so the double-buffer index is compile-time (immediate offsets).
__global__ __launch_bounds__(256, 1) void scan_kernel(
    float* buf,                       // [B][S][256]: in = ext, out = h_seq (in place)
    const float* __restrict__ W_rec,  // [256][256]
    const float* __restrict__ alphas, // [64]
    float* __restrict__ h_carry,      // [64][256]
    int layer, int write_all)
{
    __shared__ alignas(16) unsigned short h16[2][4 * 72];  // 2 x 576B
    int b = blockIdx.x;
    int tid = threadIdx.x;
    int g = tid >> 2;       // 0..63
    int kq = tid & 3;       // 0..3
    int j = kq;             // output within group this lane finalizes
    int o = tid;            // == g*4 + j

    // weights rows 4g..4g+3, cols [64kq, 64kq+64), as 32 half2 per row = 128 VGPR
    h2 wh[4][32];
    #pragma unroll
    for (int jj = 0; jj < 4; ++jj) {
        const float4* wp = (const float4*)(W_rec + (size_t)(g * 4 + jj) * 256 + kq * 64);
        #pragma unroll
        for (int m = 0; m < 16; ++m) {
            float4 wv = wp[m];
            wh[jj][2 * m]     = __builtin_bit_cast(h2, __builtin_amdgcn_cvt_pkrtz(wv.x, wv.y));
            wh[jj][2 * m + 1] = __builtin_bit_cast(h2, __builtin_amdgcn_cvt_pkrtz(wv.z, wv.w));
        }
    }

    float alpha = alphas[b];
    float onema = 1.f - alpha;
    float* bb = buf + (size_t)b * SEQ * HIDDEN;

    float h_reg = (layer == 0) ? 0.f : h_carry[b * 256 + o];
    // per-thread LDS addresses (loop-invariant)
    const uint4* hp0 = (const uint4*)((char*)&h16[0][0] + kq * 144);
    const uint4* hp1 = (const uint4*)((char*)&h16[1][0] + kq * 144);
    _Float16* wr0 = (_Float16*)((char*)&h16[0][0] + (o >> 6) * 144 + (o & 63) * 2);
    _Float16* wr1 = (_Float16*)((char*)&h16[1][0] + (o >> 6) * 144 + (o & 63) * 2);

    *wr0 = (_Float16)h_reg;                    // initial h into buffer 0
    float e_cur = bb[o];                       // ext[0]
    float e_n1  = bb[(size_t)1 * HIDDEN + o];  // ext[1]
    __syncthreads();

    auto step = [&](auto CB, int t) {
        constexpr int CUR = decltype(CB)::value;
        const uint4* hp = (CUR == 0) ? hp0 : hp1;
        // issue ALL 8 ds_read_b128 back-to-back (32 VGPRs in flight, one LDS latency)
        uint4 q0 = hp[0], q1 = hp[1], q2 = hp[2], q3 = hp[3];
        uint4 q4 = hp[4], q5 = hp[5], q6 = hp[6], q7 = hp[7];
        float e_n2 = 0.f;
        if (t + 2 < SEQ) e_n2 = bb[(size_t)(t + 2) * HIDDEN + o];  // 2-ahead prefetch

        float a0 = 0.f, a1 = 0.f, a2 = 0.f, a3 = 0.f;
        #define DOTQ(QV, M)                                                              \
        {   h2 hv0 = __builtin_bit_cast(h2, (QV).x), hv1 = __builtin_bit_cast(h2, (QV).y), \
               hv2 = __builtin_bit_cast(h2, (QV).z), hv3 = __builtin_bit_cast(h2, (QV).w); \
            a0 = FDOT2(wh[0][4*(M)], hv0, a0); a0 = FDOT2(wh[0][4*(M)+1], hv1, a0);        \
            a0 = FDOT2(wh[0][4*(M)+2], hv2, a0); a0 = FDOT2(wh[0][4*(M)+3], hv3, a0);      \
            a1 = FDOT2(wh[1][4*(M)], hv0, a1); a1 = FDOT2(wh[1][4*(M)+1], hv1, a1);        \
            a1 = FDOT2(wh[1][4*(M)+2], hv2, a1); a1 = FDOT2(wh[1][4*(M)+3], hv3, a1);      \
            a2 = FDOT2(wh[2][4*(M)], hv0, a2); a2 = FDOT2(wh[2][4*(M)+1], hv1, a2);        \
            a2 = FDOT2(wh[2][4*(M)+2], hv2, a2); a2 = FDOT2(wh[2][4*(M)+3], hv3, a2);      \
            a3 = FDOT2(wh[3][4*(M)], hv0, a3); a3 = FDOT2(wh[3][4*(M)+1], hv1, a3);        \
            a3 = FDOT2(wh[3][4*(M)+2], hv2, a3); a3 = FDOT2(wh[3][4*(M)+3], hv3, a3); }
        DOTQ(q0, 0) DOTQ(q1, 1) DOTQ(q2, 2) DOTQ(q3, 3)
        DOTQ(q4, 4) DOTQ(q5, 5) DOTQ(q6, 6) DOTQ(q7, 7)
        #undef DOTQ

        // reduce over the 4 k-segments: 2 DPP levels, no LDS
        a0 = dpp_add_xor1(a0); a1 = dpp_add_xor1(a1); a2 = dpp_add_xor1(a2); a3 = dpp_add_xor1(a3);
        a0 = dpp_add_xor2(a0); a1 = dpp_add_xor2(a1); a2 = dpp_add_xor2(a2); a3 = dpp_add_xor2(a3);
        float acc = (j == 0) ? a0 : (j == 1) ? a1 : (j == 2) ? a2 : a3;

        float act = fast_tanh(acc + e_cur);
        h_reg = alpha * h_reg + onema * act;
        *((CUR == 0) ? wr1 : wr0) = (_Float16)h_reg;         // h for next step
        if (write_all) bb[(size_t)t * HIDDEN + o] = h_reg;   // in-place h over consumed ext
        barrier_lds_only();   // lgkmcnt(0)+s_barrier; global ops stay in flight
        e_cur = e_n1;
        e_n1 = e_n2;
    };

    for (int t = 0; t < SEQ; t += 2) {
        step(std::integral_constant<int, 0>{}, t);
        step(std::integral_constant<int, 1>{}, t + 1);
    }
    h_carry[b * 256 + o] = h_reg;
}

// ---------------- final projection from h_carry ----------------
__global__ __launch_bounds__(256) void outproj_kernel(
    const float* __restrict__ h_carry, const float* __restrict__ ow, const float* __restrict__ ob,
    float* __restrict__ out)
{
    __shared__ float h_l[256];
    __shared__ float p_lds[4][64];
    int b = blockIdx.x;
    int tid = threadIdx.x;
    h_l[tid] = h_carry[b * 256 + tid];
    __syncthreads();
    int o = tid & 63, qq = tid >> 6;
    float s = 0.f;
    const float4* wp = (const float4*)(ow + o * 256 + qq * 64);
    const float4* hp = (const float4*)(h_l + qq * 64);
    #pragma unroll
    for (int m = 0; m < 16; ++m) {
        float4 wv = wp[m]; float4 hv = hp[m];
        s = fmaf(wv.x, hv.x, s); s = fmaf(wv.y, hv.y, s);
        s = fmaf(wv.z, hv.z, s); s = fmaf(wv.w, hv.w, s);
    }
    p_lds[qq][o] = s;
    __syncthreads();
    if (tid < 64)
        out[b * 64 + tid] = p_lds[0][tid] + p_lds[1][tid] + p_lds[2][tid] + p_lds[3][tid] + ob[tid];
}

extern "C" void kernel_launch(void* const* d_in, const int* in_sizes, int n_in,
                              void* d_out, int out_size, void* d_ws, size_t ws_size,
                              hipStream_t stream)
{
    const float* x     = (const float*)d_in[0];
    const float* cw1   = (const float*)d_in[1];
    const float* cb1   = (const float*)d_in[2];
    const float* cw2   = (const float*)d_in[3];
    const float* cb2   = (const float*)d_in[4];
    const float* pw    = (const float*)d_in[5];
    const float* pb    = (const float*)d_in[6];
    const float* W_rec = (const float*)d_in[7];
    const float* W_in  = (const float*)d_in[8];
    const float* bias  = (const float*)d_in[9];
    const float* tau_b = (const float*)d_in[10];
    const float* tmw   = (const float*)d_in[11];
    const float* tmb   = (const float*)d_in[12];
    const float* ow    = (const float*)d_in[13];
    const float* ob    = (const float*)d_in[14];
    float* out = (float*)d_out;

    char* ws = (char*)d_ws;
    float* alphas  = (float*)ws;                       // 192 f
    float* h_carry = (float*)(ws + 4096);              // 64*256 f
    float* bf      = (float*)(ws + 69632);             // 256 f
    float* Wf      = (float*)(ws + 70656);             // 256*128 f
    float* buf     = (float*)(ws + 1048576);           // [64][2048][256] f32 = 134.2MB

    const int M = BATCH * SEQ;          // 131072 rows
    const int ROWS_PER_WG = M / 256;    // 512

    prep_kernel<<<64, 1024, 0, stream>>>(x, cw1, cb1, cw2, cb2, tau_b, tmw, tmb, alphas);
    wf_kernel<<<256, 128, 0, stream>>>(W_in, pw, pb, bias, Wf, bf);

    // layer 0 ext = x @ Wf.T + bf  (input projection fused away)
    gemm_stream<2, 1><<<256, 512, 0, stream>>>(x, Wf, bf, buf, ROWS_PER_WG);
    scan_kernel<<<64, 256, 0, stream>>>(buf, W_rec, alphas, h_carry, 0, 1);

    gemm_stream<4, 2><<<256, 512, 0, stream>>>(buf, W_in + (size_t)1 * HIDDEN * HIDDEN,
                                               bias + 1 * HIDDEN, buf, ROWS_PER_WG);
    scan_kernel<<<64, 256, 0, stream>>>(buf, W_rec + (size_t)1 * HIDDEN * HIDDEN,
                                        alphas + 64, h_carry, 1, 1);

    gemm_stream<4, 2><<<256, 512, 0, stream>>>(buf, W_in + (size_t)2 * HIDDEN * HIDDEN,
                                               bias + 2 * HIDDEN, buf, ROWS_PER_WG);
    scan_kernel<<<64, 256, 0, stream>>>(buf, W_rec + (size_t)2 * HIDDEN * HIDDEN,
                                        alphas + 128, h_carry, 2, 0);

    outproj_kernel<<<64, 256, 0, stream>>>(h_carry, ow, ob, out);
}